// Round 8
// baseline (164.929 us; speedup 1.0000x reference)
//
#include <hip/hip_runtime.h>
#include <hip/hip_cooperative_groups.h>
#include <math.h>

namespace cg = cooperative_groups;

// Problem constants: N=8192 nodes, IN=512, OUT=8192, HEADS=1.
#define NN  8192
#define INC 512
#define NH  16    // exclusive histogram copies
#define NU  128   // u-partial blocks
#define NX  240   // x-pass blocks
#define RPB 35    // rows per x-block (ceil(8192/240))

// ws float offsets — every slot exact-written, NO pre-zeroing needed.
#define OFF_DEGP 0        // [16][NN]
#define OFF_ADVP 131072   // [16][NN]
#define OFF_UP   262144   // [128][INC]
#define OFF_TP   327680   // [240][INC]
#define OFF_SP   450560   // [16][NN]
#define OFF_XU   581632   // [NN]
#define OFF_S1P  589824   // [256]
#define OFF_S2P  590080   // [256]
#define OFF_C0   590336   // [1]

__global__ __launch_bounds__(1024) void fused(
        const float* __restrict__ x, const int* __restrict__ row,
        const int* __restrict__ col, int E,
        const float* __restrict__ weight, const float* __restrict__ bias,
        const float* __restrict__ att, const float* __restrict__ lin_w,
        const float* __restrict__ lin_b, float* __restrict__ ws,
        float* __restrict__ out) {
    cg::grid_group gg = cg::this_grid();
    __shared__ float smem[16384];                // 64 KB, re-carved per phase
    const int b = blockIdx.x, tid = threadIdx.x;
    const float* __restrict__ degp = ws + OFF_DEGP;

    // ===== P1: deg LDS-hist (b<16) | u partials (16<=b<144) | c0 (b==144) ===
    if (b < NH) {
        #pragma unroll
        for (int m = 0; m < 8; ++m) smem[tid + m * 1024] = 0.f;
        __syncthreads();
        const int per = ((E + NH - 1) / NH + 3) & ~3;
        const int e0 = b * per, e1 = (e0 + per < E) ? e0 + per : E;
        for (int i = e0 + tid * 4; i + 3 < e1; i += 4096) {
            int4 r = *(const int4*)(row + i);
            atomicAdd(&smem[r.x], 1.f); atomicAdd(&smem[r.y], 1.f);
            atomicAdd(&smem[r.z], 1.f); atomicAdd(&smem[r.w], 1.f);
        }
        for (int e = e0 + ((e1 - e0) & ~3) + tid; e < e1; e += 1024)
            atomicAdd(&smem[row[e]], 1.f);
        __syncthreads();
        float4* dst = (float4*)(ws + OFF_DEGP + (size_t)b * NN);
        dst[tid]        = ((float4*)smem)[tid];
        dst[tid + 1024] = ((float4*)smem)[tid + 1024];
    } else if (b < NH + NU) {
        float4* lds4 = (float4*)smem;
        const int r0 = (b - NH) * 64;
        const int c4 = tid & 127, rg = tid >> 7;
        float4 acc = {0.f, 0.f, 0.f, 0.f};
        #pragma unroll
        for (int it = 0; it < 8; ++it) {
            int r = r0 + rg * 8 + it;
            float w = att[r];
            float4 v = ((const float4*)(lin_w + (size_t)r * INC))[c4];
            acc.x += w * v.x; acc.y += w * v.y; acc.z += w * v.z; acc.w += w * v.w;
        }
        lds4[tid] = acc;
        __syncthreads();
        #pragma unroll
        for (int off = 4; off > 0; off >>= 1) {
            if (rg < off) {
                float4 o = lds4[(rg + off) * 128 + c4];
                float4 m = lds4[tid];
                m.x += o.x; m.y += o.y; m.z += o.z; m.w += o.w;
                lds4[tid] = m;
            }
            __syncthreads();
        }
        if (rg == 0) ((float4*)(ws + OFF_UP))[(b - NH) * 128 + c4] = lds4[c4];
    } else if (b == NH + NU) {
        float v = 0.f;
        for (int i = tid; i < NN; i += 1024) v += lin_b[i] * att[i];
        smem[tid] = v;
        __syncthreads();
        for (int off = 512; off > 0; off >>= 1) {
            if (tid < off) smem[tid] += smem[tid + off];
            __syncthreads();
        }
        if (tid == 0) ws[OFF_C0] = smem[0];
    }
    gg.sync();

    // ===== P2: adv LDS-hist (b<16) | fused t+xu pass over x (240 blocks) ===
    if (b < NH) {
        float* dl = smem;                        // dinv [8192]
        float* al = smem + 8192;                 // adv  [8192]
        #pragma unroll
        for (int m = 0; m < 8; ++m) {
            int i = tid + m * 1024;
            float d = 0.f;
            #pragma unroll
            for (int k = 0; k < NH; ++k) d += degp[k * NN + i];
            dl[i] = 1.f / sqrtf(d);
            al[i] = 0.f;
        }
        __syncthreads();
        const int per = ((E + NH - 1) / NH + 3) & ~3;
        const int e0 = b * per, e1 = (e0 + per < E) ? e0 + per : E;
        for (int i = e0 + tid * 4; i + 3 < e1; i += 4096) {
            int4 r = *(const int4*)(row + i);
            int4 c = *(const int4*)(col + i);
            atomicAdd(&al[r.x], dl[c.x]); atomicAdd(&al[r.y], dl[c.y]);
            atomicAdd(&al[r.z], dl[c.z]); atomicAdd(&al[r.w], dl[c.w]);
        }
        for (int e = e0 + ((e1 - e0) & ~3) + tid; e < e1; e += 1024)
            atomicAdd(&al[row[e]], dl[col[e]]);
        __syncthreads();
        float4* dst = (float4*)(ws + OFF_ADVP + (size_t)b * NN);
        dst[tid]        = ((float4*)al)[tid];
        dst[tid + 1024] = ((float4*)al)[tid + 1024];
    } else {
        const int bx = b - NH;                   // 0..239
        const int start = bx * RPB;
        const int cnt = (start < NN) ? ((NN - start < RPB) ? NN - start : RPB) : 0;
        float4* lds4  = (float4*)smem;           // floats 0..4095 (t tree)
        float4* u4    = (float4*)(smem + 8192);  // [128]
        float*  dinvl = smem + 8704;             // [40]
        float*  xured = smem + 8768;             // [80]
        if (tid < 128) {                         // u = sum of 128 partials
            const float4* up = (const float4*)(ws + OFF_UP);
            float4 a = {0.f, 0.f, 0.f, 0.f};
            #pragma unroll 8
            for (int q = 0; q < NU; ++q) {
                float4 v = up[q * 128 + tid];
                a.x += v.x; a.y += v.y; a.z += v.z; a.w += v.w;
            }
            u4[tid] = a;
        }
        if (tid >= 128 && tid < 168) {           // dinv for this block's rows
            int rl = tid - 128;
            if (rl < cnt) {
                float d = 0.f;
                #pragma unroll
                for (int k = 0; k < NH; ++k) d += degp[k * NN + start + rl];
                dinvl[rl] = 1.f / sqrtf(d);
            } else dinvl[rl] = 0.f;
        }
        __syncthreads();
        const int c4 = tid & 127, rg = tid >> 7, lane = tid & 63;
        float4 accT = {0.f, 0.f, 0.f, 0.f};
        float xup[5];
        #pragma unroll
        for (int it = 0; it < 5; ++it) {
            int rl = rg + it * 8;
            float xv = 0.f;
            if (rl < cnt) {
                float4 v = ((const float4*)(x + (size_t)(start + rl) * INC))[c4];
                float w = dinvl[rl];
                accT.x += w * v.x; accT.y += w * v.y; accT.z += w * v.z; accT.w += w * v.w;
                float4 uu = u4[c4];
                xv = v.x * uu.x + v.y * uu.y + v.z * uu.z + v.w * uu.w;
            }
            xup[it] = xv;
        }
        #pragma unroll
        for (int it = 0; it < 5; ++it) {
            float a = xup[it];
            #pragma unroll
            for (int off = 32; off > 0; off >>= 1) a += __shfl_down(a, off);
            if (lane == 0) xured[rg * 10 + it * 2 + ((tid >> 6) & 1)] = a;
        }
        lds4[tid] = accT;
        __syncthreads();
        if (tid < 40) {                          // rl = rg + it*8 -> rg=rl&7
            int rl = tid, rg2 = rl & 7, it2 = rl >> 3;
            if (rl < cnt)
                ws[OFF_XU + start + rl] =
                    xured[rg2 * 10 + it2 * 2] + xured[rg2 * 10 + it2 * 2 + 1];
        }
        #pragma unroll
        for (int off = 4; off > 0; off >>= 1) {
            if (rg < off) {
                float4 o = lds4[(rg + off) * 128 + c4];
                float4 m = lds4[tid];
                m.x += o.x; m.y += o.y; m.z += o.z; m.w += o.w;
                lds4[tid] = m;
            }
            __syncthreads();
        }
        if (rg == 0) ((float4*)(ws + OFF_TP))[bx * 128 + c4] = lds4[c4];
    }
    gg.sync();

    // ===== P3: s partials per (cb,kb) + scal1 block partials (256 blocks) ===
    {
        const int cb = b >> 4, kb = b & 15;
        float* tred = smem;                      // [32][33]
        float* tl   = smem + 1100;               // [32]
        float* wred = smem + 1140;               // [2]
        float4* red4 = (float4*)(smem + 4096);   // [1024]
        const float* tp = ws + OFF_TP;
        {   // rebuild t for this block's 32 columns from 240 partials
            const int cc = tid & 31, p = tid >> 5;
            float v = 0.f;
            #pragma unroll
            for (int q = 0; q < 8; ++q) {
                int pp = p + q * 32;
                if (pp < NX) v += tp[(size_t)pp * INC + cb * 32 + cc];
            }
            tred[cc * 33 + p] = v;
        }
        __syncthreads();
        if (tid < 32) {
            float v = 0.f;
            #pragma unroll
            for (int j = 0; j < 32; ++j) v += tred[tid * 33 + j];
            tl[tid] = v;
        }
        __syncthreads();
        const int k4 = tid & 127, csub = tid >> 7;
        const int k = kb * 512 + k4 * 4;
        float4 acc = {0.f, 0.f, 0.f, 0.f};
        #pragma unroll
        for (int cl = 0; cl < 4; ++cl) {
            int c = csub * 4 + cl;
            float tc = tl[c];
            float4 v = *(const float4*)(weight + (size_t)(cb * 32 + c) * NN + k);
            acc.x += tc * v.x; acc.y += tc * v.y; acc.z += tc * v.z; acc.w += tc * v.w;
        }
        red4[tid] = acc;
        __syncthreads();
        float p1 = 0.f;
        if (csub == 0) {                         // tid < 128
            float4 a = red4[k4];
            #pragma unroll
            for (int j = 1; j < 8; ++j) {
                float4 o = red4[j * 128 + k4];
                a.x += o.x; a.y += o.y; a.z += o.z; a.w += o.w;
            }
            ((float4*)(ws + OFF_SP))[cb * 2048 + kb * 128 + k4] = a;
            float4 a2 = ((const float4*)(att + NN))[kb * 128 + k4];
            p1 = a.x * a2.x + a.y * a2.y + a.z * a2.z + a.w * a2.w;
        }
        #pragma unroll
        for (int off = 32; off > 0; off >>= 1) p1 += __shfl_down(p1, off);
        if (csub == 0 && (tid & 63) == 0) wred[tid >> 6] = p1;
        __syncthreads();
        if (tid == 0) ws[OFF_S1P + b] = wred[0] + wred[1];
    }
    gg.sync();

    // ===== P4: scal1 reduce (redundant) + scal2 block partials ===============
    float advv = 0.f;
    {
        smem[tid] = (tid < 256) ? ws[OFF_S1P + tid] : 0.f;
        __syncthreads();
        for (int off = 512; off > 0; off >>= 1) {
            if (tid < off) smem[tid] += smem[tid + off];
            __syncthreads();
        }
        const float scal1 = smem[0];
        const float c0 = ws[OFF_C0];
        __syncthreads();
        float part = 0.f;
        if (tid < 32) {                          // this block's 32 nodes
            int i = b * 32 + tid;
            float a8 = 0.f, sv = 0.f;
            #pragma unroll
            for (int kk = 0; kk < NH; ++kk) {
                a8 += ws[OFF_ADVP + kk * NN + i];
                sv += ws[OFF_SP   + kk * NN + i];
            }
            advv = a8;
            float a = ws[OFF_XU + i] + c0 + a8 * scal1;
            float lr = a > 0.f ? a : 0.2f * a;
            part = lr * sv;
        }
        #pragma unroll
        for (int off = 16; off > 0; off >>= 1) part += __shfl_down(part, off);
        if (tid == 0) ws[OFF_S2P + b] = part;
    }
    gg.sync();

    // ===== P5: scal2 reduce (redundant) + out ================================
    {
        smem[tid] = (tid < 256) ? ws[OFF_S2P + tid] : 0.f;
        __syncthreads();
        for (int off = 512; off > 0; off >>= 1) {
            if (tid < off) smem[tid] += smem[tid + off];
            __syncthreads();
        }
        const float sc2 = smem[0];
        if (tid < 32) {
            int i = b * 32 + tid;
            float v = advv * sc2 + bias[i];
            out[i] = v > 0.f ? v : 0.f;
        }
    }
}

// ---------------------------------------------------------------------------
extern "C" void kernel_launch(void* const* d_in, const int* in_sizes, int n_in,
                              void* d_out, int out_size, void* d_ws, size_t ws_size,
                              hipStream_t stream) {
    const float* x      = (const float*)d_in[0];   // [8192, 512]
    const int*   eidx   = (const int*)d_in[1];     // [2, E]
    const float* weight = (const float*)d_in[2];   // [512, 8192]
    const float* bias   = (const float*)d_in[3];   // [8192]
    const float* att    = (const float*)d_in[4];   // [16384]
    const float* lin_w  = (const float*)d_in[5];   // [8192, 512]
    const float* lin_b  = (const float*)d_in[6];   // [8192]

    int E = in_sizes[1] / 2;
    const int* row = eidx;
    const int* col = eidx + E;
    float* ws  = (float*)d_ws;
    float* out = (float*)d_out;

    void* args[] = {(void*)&x, (void*)&row, (void*)&col, (void*)&E,
                    (void*)&weight, (void*)&bias, (void*)&att,
                    (void*)&lin_w, (void*)&lin_b, (void*)&ws, (void*)&out};
    hipLaunchCooperativeKernel((void*)fused, dim3(256), dim3(1024),
                               args, 0, stream);
}

// Round 9
// 96.335 us; speedup vs baseline: 1.7120x; 1.7120x over previous
//
#include <hip/hip_runtime.h>
#include <math.h>

// Problem constants: N=8192 nodes, IN=512, OUT=8192, HEADS=1.
#define NN   8192
#define INC  512
#define NC   8     // deg histogram copies (exact-write, no pre-zero needed)
#define NUP  64    // u-partial blocks (128 rows each)
#define NV   128   // v blocks (4 rows of W each)
#define NADV 32    // adv edge-atomic blocks
#define NXB  128   // x-pass blocks (64 rows each)

// ws float offsets
#define OFF_DEGP 0                    // [8][NN]   exact-write
#define OFF_UP   (NC * NN)            // [64][512] exact-write
#define OFF_V    (NC * NN + NUP*INC)  // [512]     exact-write
#define OFF_T    (OFF_V + 512)        // [512]     atomic, zeroed by K1
#define OFF_MISC (OFF_T + 512)        // [0]=c0, [1]=done(int), zeroed by K1
#define OFF_ADV  (OFF_MISC + 8)       // [NN]      atomic, zeroed by K1
#define OFF_XU   (OFF_ADV + NN)       // [NN]      exact-write
#define OFF_S2P  (OFF_XU + NN)        // [256]     agent-scope atomic store

// ===========================================================================
// K1: b<8: deg LDS-hist | 8..71: u partials | 72..199: v=W@a2 | 200: c0+zeros
__global__ __launch_bounds__(1024) void k1(
        const float* __restrict__ lin_w, const float* __restrict__ att,
        const float* __restrict__ lin_b, const float* __restrict__ weight,
        const int* __restrict__ row, int E, float* __restrict__ ws) {
    __shared__ float smem[8192];
    const int b = blockIdx.x, tid = threadIdx.x;

    if (b < NC) {                                // ---- deg histogram ----
        #pragma unroll
        for (int m = 0; m < 8; ++m) smem[tid + m * 1024] = 0.f;
        __syncthreads();
        const int per = ((E + NC - 1) / NC + 3) & ~3;
        const int e0 = b * per, e1 = (e0 + per < E) ? e0 + per : E;
        for (int i = e0 + tid * 4; i + 3 < e1; i += 4096) {
            int4 r = *(const int4*)(row + i);
            atomicAdd(&smem[r.x], 1.f); atomicAdd(&smem[r.y], 1.f);
            atomicAdd(&smem[r.z], 1.f); atomicAdd(&smem[r.w], 1.f);
        }
        for (int e = e0 + ((e1 - e0) & ~3) + tid; e < e1; e += 1024)
            atomicAdd(&smem[row[e]], 1.f);
        __syncthreads();
        float4* dst = (float4*)(ws + OFF_DEGP + (size_t)b * NN);
        dst[tid]        = ((float4*)smem)[tid];
        dst[tid + 1024] = ((float4*)smem)[tid + 1024];
    } else if (b < NC + NUP) {                   // ---- u partials (128 rows) --
        float4* lds4 = (float4*)smem;
        const int r0 = (b - NC) * 128;
        const int c4 = tid & 127, rg = tid >> 7;
        float4 acc = {0.f, 0.f, 0.f, 0.f};
        #pragma unroll
        for (int it = 0; it < 16; ++it) {
            int r = r0 + rg * 16 + it;
            float w = att[r];
            float4 v = ((const float4*)(lin_w + (size_t)r * INC))[c4];
            acc.x += w * v.x; acc.y += w * v.y; acc.z += w * v.z; acc.w += w * v.w;
        }
        lds4[tid] = acc;
        __syncthreads();
        #pragma unroll
        for (int off = 4; off > 0; off >>= 1) {
            if (rg < off) {
                float4 o = lds4[(rg + off) * 128 + c4];
                float4 m = lds4[tid];
                m.x += o.x; m.y += o.y; m.z += o.z; m.w += o.w;
                lds4[tid] = m;
            }
            __syncthreads();
        }
        if (rg == 0) ((float4*)(ws + OFF_UP))[(b - NC) * 128 + c4] = lds4[c4];
    } else if (b < NC + NUP + NV) {              // ---- v[c] = W[c,:].a2 ----
        const int r0 = (b - NC - NUP) * 4;
        const int rg = tid >> 8, kl = tid & 255;
        const int c = r0 + rg;
        const float4* wrow = (const float4*)(weight + (size_t)c * NN);
        const float4* a2   = (const float4*)(att + NN);
        float acc = 0.f;
        #pragma unroll
        for (int q = 0; q < 8; ++q) {
            float4 wv = wrow[kl + q * 256];
            float4 av = a2[kl + q * 256];
            acc += wv.x * av.x + wv.y * av.y + wv.z * av.z + wv.w * av.w;
        }
        smem[rg * 256 + kl] = acc;
        __syncthreads();
        for (int off = 128; off > 0; off >>= 1) {
            if (kl < off) smem[rg * 256 + kl] += smem[rg * 256 + kl + off];
            __syncthreads();
        }
        if (kl == 0) ws[OFF_V + c] = smem[rg * 256];
    } else {                                     // ---- c0 + zero t/adv/done --
        float v = 0.f;
        for (int i = tid; i < NN; i += 1024) v += lin_b[i] * att[i];
        smem[tid] = v;
        __syncthreads();
        for (int off = 512; off > 0; off >>= 1) {
            if (tid < off) smem[tid] += smem[tid + off];
            __syncthreads();
        }
        if (tid == 0) {
            ws[OFF_MISC] = smem[0];
            *(int*)(ws + OFF_MISC + 1) = 0;      // done counter
        }
        if (tid < 512) ws[OFF_T + tid] = 0.f;
        for (int i = tid; i < NN; i += 1024) ws[OFF_ADV + i] = 0.f;
    }
}

// ===========================================================================
// K2: b<32: adv[row[e]] += dinv[col[e]] (dinv rebuilt in LDS; global atomics)
//     b>=32: x-pass 64 rows: t-partial -> global-atomic t; xu exact.
__global__ __launch_bounds__(1024) void k2(
        const float* __restrict__ x, const int* __restrict__ row,
        const int* __restrict__ col, int E, float* __restrict__ ws) {
    __shared__ float smem[8192];
    const int b = blockIdx.x, tid = threadIdx.x;
    const float* __restrict__ degp = ws + OFF_DEGP;

    if (b < NADV) {                              // ---- adv edge pass ----
        #pragma unroll
        for (int m = 0; m < 8; ++m) {            // rebuild full dinv in LDS
            int i = tid + m * 1024;
            float d = 0.f;
            #pragma unroll
            for (int k = 0; k < NC; ++k) d += degp[k * NN + i];
            smem[i] = 1.f / sqrtf(d);
        }
        __syncthreads();
        float* __restrict__ adv = ws + OFF_ADV;
        const int per = ((E + NADV - 1) / NADV + 3) & ~3;
        const int e0 = b * per, e1 = (e0 + per < E) ? e0 + per : E;
        for (int i = e0 + tid * 4; i + 3 < e1; i += 4096) {
            int4 r = *(const int4*)(row + i);
            int4 c = *(const int4*)(col + i);
            atomicAdd(&adv[r.x], smem[c.x]); atomicAdd(&adv[r.y], smem[c.y]);
            atomicAdd(&adv[r.z], smem[c.z]); atomicAdd(&adv[r.w], smem[c.w]);
        }
        for (int e = e0 + ((e1 - e0) & ~3) + tid; e < e1; e += 1024)
            atomicAdd(&adv[row[e]], smem[col[e]]);
    } else {                                     // ---- fused t + xu over x ---
        float4* lds4  = (float4*)smem;           // floats    0..4095
        float4* u4    = (float4*)(smem + 4096);  // floats 4096..4607
        float*  dinvl = smem + 4608;             // [64]
        float*  xured = smem + 4672;             // [128]
        const int bx = b - NADV;
        const int r0 = bx * 64;
        if (tid < 128) {                         // u = sum of 64 partials
            const float4* up = (const float4*)(ws + OFF_UP);
            float4 a = {0.f, 0.f, 0.f, 0.f};
            #pragma unroll 8
            for (int q = 0; q < NUP; ++q) {
                float4 v = up[q * 128 + tid];
                a.x += v.x; a.y += v.y; a.z += v.z; a.w += v.w;
            }
            u4[tid] = a;
        }
        if (tid >= 128 && tid < 192) {           // dinv for this block's rows
            int rl = tid - 128;
            float d = 0.f;
            #pragma unroll
            for (int k = 0; k < NC; ++k) d += degp[k * NN + r0 + rl];
            dinvl[rl] = 1.f / sqrtf(d);
        }
        __syncthreads();
        const int c4 = tid & 127, rg = tid >> 7, lane = tid & 63;
        float4 accT = {0.f, 0.f, 0.f, 0.f};
        float xup[8];
        #pragma unroll
        for (int it = 0; it < 8; ++it) {
            int rl = rg + it * 8;
            float4 v = ((const float4*)(x + (size_t)(r0 + rl) * INC))[c4];
            float w = dinvl[rl];
            accT.x += w * v.x; accT.y += w * v.y; accT.z += w * v.z; accT.w += w * v.w;
            float4 uu = u4[c4];
            xup[it] = v.x * uu.x + v.y * uu.y + v.z * uu.z + v.w * uu.w;
        }
        #pragma unroll
        for (int it = 0; it < 8; ++it) {
            float a = xup[it];
            #pragma unroll
            for (int off = 32; off > 0; off >>= 1) a += __shfl_down(a, off);
            if (lane == 0) xured[rg * 16 + it * 2 + ((tid >> 6) & 1)] = a;
        }
        lds4[tid] = accT;
        __syncthreads();
        if (tid < 64) {
            int rg2 = tid >> 3, it2 = tid & 7;
            ws[OFF_XU + r0 + rg2 + it2 * 8] =
                xured[rg2 * 16 + it2 * 2] + xured[rg2 * 16 + it2 * 2 + 1];
        }
        #pragma unroll
        for (int off = 4; off > 0; off >>= 1) {
            if (rg < off) {
                float4 o = lds4[(rg + off) * 128 + c4];
                float4 m = lds4[tid];
                m.x += o.x; m.y += o.y; m.z += o.z; m.w += o.w;
                lds4[tid] = m;
            }
            __syncthreads();
        }
        if (rg == 0) {                           // 512 light global atomics
            float4 a = lds4[c4];
            float* t = ws + OFF_T;
            atomicAdd(&t[4 * c4 + 0], a.x); atomicAdd(&t[4 * c4 + 1], a.y);
            atomicAdd(&t[4 * c4 + 2], a.z); atomicAdd(&t[4 * c4 + 3], a.w);
        }
    }
}

// ===========================================================================
// K3 (256 blocks, k/i-window of 32 each):
//   scal1 = t.v (redundant in-block); s[k] = full-c dot over W slice;
//   s2 partial = sum s[i]*leaky_relu(xu[i]+c0+adv[i]*scal1);
//   last-done block: scal2 = sum(256 partials, fixed order) -> out.
__global__ __launch_bounds__(1024) void k3(
        const float* __restrict__ weight, const float* __restrict__ bias,
        float* __restrict__ ws, float* __restrict__ out) {
    __shared__ float smem[4096];
    __shared__ int lastf;
    float* t_lds = smem;            // [512]
    float* red   = smem + 512;      // [512]
    float* gmat  = smem + 1024;     // [32*33]
    float* s_lds = smem + 2112;     // [32]
    const int b = blockIdx.x, tid = threadIdx.x;

    if (tid < 512) {
        float tv = ws[OFF_T + tid];
        t_lds[tid] = tv;
        red[tid] = tv * ws[OFF_V + tid];
    }
    __syncthreads();
    for (int off = 256; off > 0; off >>= 1) {
        if (tid < off) red[tid] += red[tid + off];
        __syncthreads();
    }
    const float scal1 = red[0];

    const int g = tid >> 5, kl = tid & 31;
    const int k = b * 32 + kl;
    float acc = 0.f;
    #pragma unroll
    for (int q = 0; q < 16; ++q) {
        int c = g + (q << 5);
        acc += t_lds[c] * weight[(size_t)c * NN + k];
    }
    gmat[g * 33 + kl] = acc;
    __syncthreads();
    if (tid < 32) {
        float v = 0.f;
        #pragma unroll
        for (int j = 0; j < 32; ++j) v += gmat[j * 33 + tid];
        s_lds[tid] = v;
    }
    __syncthreads();

    float part = 0.f;
    if (tid < 32) {
        int i = b * 32 + tid;
        float a = ws[OFF_XU + i] + ws[OFF_MISC] + ws[OFF_ADV + i] * scal1;
        float lr = a > 0.f ? a : 0.2f * a;
        part = s_lds[tid] * lr;
        #pragma unroll
        for (int off = 16; off > 0; off >>= 1) part += __shfl_down(part, off);
    }
    if (tid == 0) {
        __hip_atomic_store(&ws[OFF_S2P + b], part, __ATOMIC_RELEASE,
                           __HIP_MEMORY_SCOPE_AGENT);
        int old = __hip_atomic_fetch_add((int*)(ws + OFF_MISC + 1), 1,
                                         __ATOMIC_ACQ_REL,
                                         __HIP_MEMORY_SCOPE_AGENT);
        lastf = (old == 255);
    }
    __syncthreads();
    if (!lastf) return;

    // ---- last block: scal2 + out (deterministic fixed-order tree) ----
    float p2 = (tid < 256)
        ? __hip_atomic_load(&ws[OFF_S2P + tid], __ATOMIC_ACQUIRE,
                            __HIP_MEMORY_SCOPE_AGENT)
        : 0.f;
    __syncthreads();                 // smem reuse safe
    smem[tid] = p2;
    __syncthreads();
    for (int off = 512; off > 0; off >>= 1) {
        if (tid < off) smem[tid] += smem[tid + off];
        __syncthreads();
    }
    const float scal2 = smem[0];
    #pragma unroll
    for (int m = 0; m < 8; ++m) {
        int i = tid + m * 1024;
        float v = ws[OFF_ADV + i] * scal2 + bias[i];
        out[i] = v > 0.f ? v : 0.f;
    }
}

// ===========================================================================
extern "C" void kernel_launch(void* const* d_in, const int* in_sizes, int n_in,
                              void* d_out, int out_size, void* d_ws, size_t ws_size,
                              hipStream_t stream) {
    const float* x      = (const float*)d_in[0];   // [8192, 512]
    const int*   eidx   = (const int*)d_in[1];     // [2, E]
    const float* weight = (const float*)d_in[2];   // [512, 8192]
    const float* bias   = (const float*)d_in[3];   // [8192]
    const float* att    = (const float*)d_in[4];   // [16384]
    const float* lin_w  = (const float*)d_in[5];   // [8192, 512]
    const float* lin_b  = (const float*)d_in[6];   // [8192]

    const int E = in_sizes[1] / 2;
    const int* row = eidx;
    const int* col = eidx + E;
    float* ws  = (float*)d_ws;
    float* out = (float*)d_out;

    k1<<<NC + NUP + NV + 1, 1024, 0, stream>>>(lin_w, att, lin_b, weight, row, E, ws);
    k2<<<NADV + NXB,        1024, 0, stream>>>(x, row, col, E, ws);
    k3<<<256,               1024, 0, stream>>>(weight, bias, ws, out);
}

// Round 11
// 55.470 us; speedup vs baseline: 2.9733x; 1.7367x over previous
//
#include <hip/hip_runtime.h>
#include <math.h>

// Problem constants: N=8192 nodes, IN=512, OUT=8192, HEADS=1.
#define NN   8192
#define INC  512
#define NDEG 64    // deg LDS-hist blocks/copies
#define NU   64    // u-partial blocks (128 rows each)
#define NV   128   // v blocks (4 rows of W each)
#define NADV 64    // adv LDS-hist blocks/copies
#define NXB  128   // x-pass blocks (64 rows each)
#define NK4  256   // k4 blocks

// ws float offsets — every slot exact-written; counters zeroed by K1 (the
// R8-proven mechanism: zero in a prior kernel, check old == N-1).
#define OFF_DEGP 0u          // [64][NN]
#define OFF_ADVP 524288u     // [64][NN]
#define OFF_UP   1048576u    // [64][INC]
#define OFF_TP   1081344u    // [128][INC]
#define OFF_V    1146880u    // [512]
#define OFF_T    1147392u    // [512]
#define OFF_DINV 1147904u    // [NN]
#define OFF_XU   1156096u    // [NN]
#define OFF_ADVF 1164288u    // [NN]
#define OFF_S2P  1172480u    // [256]
#define OFF_SC   1172736u    // [0]=c0, [1]=scal1
#define OFF_CNT1 1172744u    // x-pass done-counter (zeroed by K1)
#define OFF_CNT2 1172752u    // k4 done-counter    (zeroed by K1)

__device__ __forceinline__ unsigned bump(float* ws, unsigned off) {
    return __hip_atomic_fetch_add((unsigned*)(ws + off), 1u,
                                  __ATOMIC_ACQ_REL, __HIP_MEMORY_SCOPE_AGENT);
}

// ===========================================================================
// K1: b<64: deg LDS-hist -> DEGP[b] | 64..127: u partials | 128..255: v=W@a2
//     b=256: c0 + zero CNT1/CNT2
__global__ __launch_bounds__(1024) void k1(
        const float* __restrict__ lin_w, const float* __restrict__ att,
        const float* __restrict__ lin_b, const float* __restrict__ weight,
        const int* __restrict__ row, int E, float* __restrict__ ws) {
    __shared__ float smem[8192];
    const int b = blockIdx.x, tid = threadIdx.x;

    if (b < NDEG) {                              // ---- deg histogram ----
        #pragma unroll
        for (int m = 0; m < 8; ++m) smem[tid + m * 1024] = 0.f;
        __syncthreads();
        const int per4 = (E >> 2) / NDEG;        // 1024 int4 chunks per block
        const int4* r4 = (const int4*)row;
        for (int q = tid; q < per4; q += 1024) {
            int4 r = r4[b * per4 + q];
            atomicAdd(&smem[r.x], 1.f); atomicAdd(&smem[r.y], 1.f);
            atomicAdd(&smem[r.z], 1.f); atomicAdd(&smem[r.w], 1.f);
        }
        if (b == NDEG - 1)                       // generic tail
            for (int e = per4 * 4 * NDEG + tid; e < E; e += 1024)
                atomicAdd(&smem[row[e]], 1.f);
        __syncthreads();
        float4* dst = (float4*)(ws + OFF_DEGP) + b * 2048;
        dst[tid]        = ((float4*)smem)[tid];
        dst[tid + 1024] = ((float4*)smem)[tid + 1024];
    } else if (b < NDEG + NU) {                  // ---- u partials ----
        float4* lds4 = (float4*)smem;
        const int r0 = (b - NDEG) * 128;
        const int c4 = tid & 127, rg = tid >> 7;
        float4 acc = {0.f, 0.f, 0.f, 0.f};
        #pragma unroll
        for (int it = 0; it < 16; ++it) {
            int r = r0 + rg * 16 + it;
            float w = att[r];
            float4 v = ((const float4*)(lin_w + (size_t)r * INC))[c4];
            acc.x += w * v.x; acc.y += w * v.y; acc.z += w * v.z; acc.w += w * v.w;
        }
        lds4[tid] = acc;
        __syncthreads();
        #pragma unroll
        for (int off = 4; off > 0; off >>= 1) {
            if (rg < off) {
                float4 o = lds4[(rg + off) * 128 + c4];
                float4 m = lds4[tid];
                m.x += o.x; m.y += o.y; m.z += o.z; m.w += o.w;
                lds4[tid] = m;
            }
            __syncthreads();
        }
        if (rg == 0) ((float4*)(ws + OFF_UP))[(b - NDEG) * 128 + c4] = lds4[c4];
    } else if (b < NDEG + NU + NV) {             // ---- v[c] = W[c,:].a2 ----
        const int r0 = (b - NDEG - NU) * 4;
        const int rg = tid >> 8, kl = tid & 255;
        const int c = r0 + rg;
        const float4* wrow = (const float4*)(weight + (size_t)c * NN);
        const float4* a2   = (const float4*)(att + NN);
        float acc = 0.f;
        #pragma unroll
        for (int q = 0; q < 8; ++q) {
            float4 wv = wrow[kl + q * 256];
            float4 av = a2[kl + q * 256];
            acc += wv.x * av.x + wv.y * av.y + wv.z * av.z + wv.w * av.w;
        }
        smem[rg * 256 + kl] = acc;
        __syncthreads();
        for (int off = 128; off > 0; off >>= 1) {
            if (kl < off) smem[rg * 256 + kl] += smem[rg * 256 + kl + off];
            __syncthreads();
        }
        if (kl == 0) ws[OFF_V + c] = smem[rg * 256];
    } else {                                     // ---- c0 + counter zeroing --
        float v = 0.f;
        for (int i = tid; i < NN; i += 1024) v += lin_b[i] * att[i];
        smem[tid] = v;
        __syncthreads();
        for (int off = 512; off > 0; off >>= 1) {
            if (tid < off) smem[tid] += smem[tid + off];
            __syncthreads();
        }
        if (tid == 0) {
            ws[OFF_SC] = smem[0];
            *(unsigned*)(ws + OFF_CNT1) = 0u;    // kernel boundary orders these
            *(unsigned*)(ws + OFF_CNT2) = 0u;
        }
    }
}

// ===========================================================================
// K2 (128 blocks, 64 rows each): rebuild u from partials; dinv for own rows
// from DEGP (also stored to OFF_DINV for K3); t partial (exact) + xu;
// last-done block -> t finalize + scal1 = t.v.
__global__ __launch_bounds__(1024) void k2(
        const float* __restrict__ x, float* __restrict__ ws) {
    __shared__ float smem[8960];
    __shared__ int isLast;
    float4* lds4  = (float4*)smem;           // floats    0..4095 (t tree)
    float4* ured  = (float4*)(smem + 4096);  // floats 4096..8191
    float4* u4    = (float4*)(smem + 8192);  // floats 8192..8703
    float*  dinvl = smem + 8704;             // [64]
    float*  xured = smem + 8768;             // [128]
    const int b = blockIdx.x, tid = threadIdx.x;
    const int r0 = b * 64;
    const int c4 = tid & 127, rg = tid >> 7, lane = tid & 63;

    {                                        // u = sum of 64 partials
        const float4* up = (const float4*)(ws + OFF_UP);
        float4 a = {0.f, 0.f, 0.f, 0.f};
        #pragma unroll
        for (int q = 0; q < 8; ++q) {
            float4 v = up[(rg * 8 + q) * 128 + c4];
            a.x += v.x; a.y += v.y; a.z += v.z; a.w += v.w;
        }
        ured[rg * 128 + c4] = a;
    }
    if (tid >= 128 && tid < 192) {           // dinv for this block's 64 rows
        int rl = tid - 128;
        const float* degp = ws + OFF_DEGP;
        float d = 0.f;
        #pragma unroll 8
        for (int cp = 0; cp < NDEG; ++cp) d += degp[cp * NN + r0 + rl];
        float dvv = 1.f / sqrtf(d);
        dinvl[rl] = dvv;
        ws[OFF_DINV + r0 + rl] = dvv;        // exact-write slice for K3
    }
    __syncthreads();
    if (tid < 128) {
        float4 a = {0.f, 0.f, 0.f, 0.f};
        #pragma unroll
        for (int g = 0; g < 8; ++g) {
            float4 v = ured[g * 128 + tid];
            a.x += v.x; a.y += v.y; a.z += v.z; a.w += v.w;
        }
        u4[tid] = a;
    }
    __syncthreads();

    float4 accT = {0.f, 0.f, 0.f, 0.f};
    float xup[8];
    #pragma unroll
    for (int it = 0; it < 8; ++it) {
        int rl = rg + it * 8;
        float4 v = ((const float4*)(x + (size_t)(r0 + rl) * INC))[c4];
        float w = dinvl[rl];
        accT.x += w * v.x; accT.y += w * v.y; accT.z += w * v.z; accT.w += w * v.w;
        float4 uu = u4[c4];
        xup[it] = v.x * uu.x + v.y * uu.y + v.z * uu.z + v.w * uu.w;
    }
    #pragma unroll
    for (int it = 0; it < 8; ++it) {
        float a = xup[it];
        #pragma unroll
        for (int off = 32; off > 0; off >>= 1) a += __shfl_down(a, off);
        if (lane == 0) xured[rg * 16 + it * 2 + ((tid >> 6) & 1)] = a;
    }
    lds4[tid] = accT;
    __syncthreads();
    if (tid < 64) {
        int rg2 = tid >> 3, it2 = tid & 7;
        ws[OFF_XU + r0 + rg2 + it2 * 8] =
            xured[rg2 * 16 + it2 * 2] + xured[rg2 * 16 + it2 * 2 + 1];
    }
    #pragma unroll
    for (int off = 4; off > 0; off >>= 1) {
        if (rg < off) {
            float4 o = lds4[(rg + off) * 128 + c4];
            float4 m = lds4[tid];
            m.x += o.x; m.y += o.y; m.z += o.z; m.w += o.w;
            lds4[tid] = m;
        }
        __syncthreads();
    }
    if (rg == 0) ((float4*)(ws + OFF_TP))[b * 128 + c4] = lds4[c4];
    if (tid == 0) {
        unsigned old = bump(ws, OFF_CNT1);   // CNT1 zeroed by K1 this launch
        isLast = (old == NXB - 1);
    }
    __syncthreads();
    if (!isLast) return;
    // ---- t finalize + scal1 = t.v ----
    if (tid < 512) {
        const float* tp = ws + OFF_TP;
        float tv = 0.f;
        #pragma unroll 4
        for (int p = 0; p < NXB; ++p) tv += tp[p * INC + tid];
        ws[OFF_T + tid] = tv;
        smem[tid] = tv * ws[OFF_V + tid];
    }
    __syncthreads();
    for (int off = 256; off > 0; off >>= 1) {
        if (tid < off) smem[tid] += smem[tid + off];
        __syncthreads();
    }
    if (tid == 0) ws[OFF_SC + 1] = smem[0];
}

// ===========================================================================
// K3 (64 blocks): adv LDS-hist. dinv read finalized from OFF_DINV (32KB hot).
// Exact-write ADVP[b]; no counters.
__global__ __launch_bounds__(1024) void k3(
        const int* __restrict__ row, const int* __restrict__ col, int E,
        float* __restrict__ ws) {
    __shared__ float smem[16384];
    const int b = blockIdx.x, tid = threadIdx.x;
    float* dl = smem;                        // dinv [8192]
    float* al = smem + 8192;                 // adv  [8192]
    const float4* dv = (const float4*)(ws + OFF_DINV);
    ((float4*)dl)[tid]        = dv[tid];
    ((float4*)dl)[tid + 1024] = dv[tid + 1024];
    #pragma unroll
    for (int m = 0; m < 8; ++m) al[tid + m * 1024] = 0.f;
    __syncthreads();
    const int per4 = (E >> 2) / NADV;        // 1024
    const int4* r4  = (const int4*)row;
    const int4* c4p = (const int4*)col;
    for (int q = tid; q < per4; q += 1024) {
        int4 r = r4[b * per4 + q];
        int4 c = c4p[b * per4 + q];
        atomicAdd(&al[r.x], dl[c.x]); atomicAdd(&al[r.y], dl[c.y]);
        atomicAdd(&al[r.z], dl[c.z]); atomicAdd(&al[r.w], dl[c.w]);
    }
    if (b == NADV - 1)
        for (int e = per4 * 4 * NADV + tid; e < E; e += 1024)
            atomicAdd(&al[row[e]], dl[col[e]]);
    __syncthreads();
    float4* dst = (float4*)(ws + OFF_ADVP) + b * 2048;
    dst[tid]        = ((float4*)al)[tid];
    dst[tid + 1024] = ((float4*)al)[tid + 1024];
}

// ===========================================================================
// K4 (256 blocks, 32-wide k/i windows): s[k] full-c dot over W; adv = sum of
// 64 ADVP copies; alpha + s2 partial; last-done block: scal2 + out.
__global__ __launch_bounds__(1024) void k4(
        const float* __restrict__ weight, const float* __restrict__ bias,
        float* __restrict__ ws, float* __restrict__ out) {
    __shared__ float smem[4096];
    __shared__ int isLast;
    float* t_lds = smem;            // [512]
    float* gmat  = smem + 512;      // [32*33]
    float* amat  = smem + 1600;     // [32*33]
    const int b = blockIdx.x, tid = threadIdx.x;

    if (tid < 512) t_lds[tid] = ws[OFF_T + tid];
    __syncthreads();

    const int g = tid >> 5, kl = tid & 31;
    const int k = b * 32 + kl;
    float acc = 0.f;
    #pragma unroll
    for (int q = 0; q < 16; ++q) {
        int c = g + (q << 5);
        acc += t_lds[c] * weight[(size_t)c * NN + k];
    }
    gmat[g * 33 + kl] = acc;
    {   // adv copy-pairs: group g sums copies 2g, 2g+1 for node kl
        const float* ap = ws + OFF_ADVP;
        int i = b * 32 + kl;
        amat[g * 33 + kl] = ap[(size_t)(2 * g) * NN + i]
                          + ap[(size_t)(2 * g + 1) * NN + i];
    }
    __syncthreads();
    if (tid < 32) {
        float sv = 0.f, av = 0.f;
        #pragma unroll
        for (int j = 0; j < 32; ++j) {
            sv += gmat[j * 33 + tid];
            av += amat[j * 33 + tid];
        }
        int i = b * 32 + tid;
        float a  = ws[OFF_XU + i] + ws[OFF_SC] + av * ws[OFF_SC + 1];
        float lr = a > 0.f ? a : 0.2f * a;
        float part = sv * lr;
        ws[OFF_ADVF + i] = av;
        #pragma unroll
        for (int off = 16; off > 0; off >>= 1) part += __shfl_down(part, off);
        if (tid == 0) ws[OFF_S2P + b] = part;
    }
    __syncthreads();
    if (tid == 0) {
        unsigned old = bump(ws, OFF_CNT2);   // CNT2 zeroed by K1 this launch
        isLast = (old == NK4 - 1);
    }
    __syncthreads();
    if (!isLast) return;

    // ---- last block: scal2 (fixed-order tree, deterministic) + out ----
    smem[tid] = (tid < 256) ? ws[OFF_S2P + tid] : 0.f;
    __syncthreads();
    for (int off = 512; off > 0; off >>= 1) {
        if (tid < off) smem[tid] += smem[tid + off];
        __syncthreads();
    }
    const float s2 = smem[0];
    #pragma unroll
    for (int m = 0; m < 8; ++m) {
        int i = tid + m * 1024;
        float v = ws[OFF_ADVF + i] * s2 + bias[i];
        out[i] = v > 0.f ? v : 0.f;
    }
}

// ===========================================================================
extern "C" void kernel_launch(void* const* d_in, const int* in_sizes, int n_in,
                              void* d_out, int out_size, void* d_ws, size_t ws_size,
                              hipStream_t stream) {
    const float* x      = (const float*)d_in[0];   // [8192, 512]
    const int*   eidx   = (const int*)d_in[1];     // [2, E]
    const float* weight = (const float*)d_in[2];   // [512, 8192]
    const float* bias   = (const float*)d_in[3];   // [8192]
    const float* att    = (const float*)d_in[4];   // [16384]
    const float* lin_w  = (const float*)d_in[5];   // [8192, 512]
    const float* lin_b  = (const float*)d_in[6];   // [8192]

    const int E = in_sizes[1] / 2;
    const int* row = eidx;
    const int* col = eidx + E;
    float* ws  = (float*)d_ws;
    float* out = (float*)d_out;

    k1<<<NDEG + NU + NV + 1, 1024, 0, stream>>>(lin_w, att, lin_b, weight, row, E, ws);
    k2<<<NXB,  1024, 0, stream>>>(x, ws);
    k3<<<NADV, 1024, 0, stream>>>(row, col, E, ws);
    k4<<<NK4,  1024, 0, stream>>>(weight, bias, ws, out);
}

// Round 12
// 46.058 us; speedup vs baseline: 3.5809x; 1.2044x over previous
//
#include <hip/hip_runtime.h>
#include <math.h>

// Problem constants: N=8192 nodes, IN=512, OUT=8192, HEADS=1.
#define NN   8192
#define INC  512
#define NDEG 128   // deg LDS-hist blocks/copies
#define NU   128   // u-partial blocks (64 rows each)
#define NV   128   // v blocks (4 rows of W each)
#define NADV 128   // adv LDS-hist blocks/copies
#define NXB  256   // x-pass blocks (32 rows each)
#define NK4  256   // k4 blocks

// ws float offsets — every slot exact-written; CNT2 zeroed by K1 (R8-proven
// mechanism: zero in a prior kernel, check old == N-1).
#define OFF_DEGP 0u          // [128][NN]
#define OFF_ADVP 1048576u    // [128][NN]
#define OFF_UP   2097152u    // [128][INC]
#define OFF_TP   2162688u    // [256][INC]
#define OFF_V    2293760u    // [512]
#define OFF_T    2294272u    // [512]
#define OFF_DINV 2294784u    // [NN]
#define OFF_XU   2302976u    // [NN]
#define OFF_ADVF 2311168u    // [NN]
#define OFF_S2P  2319360u    // [256]
#define OFF_SC   2319616u    // [0]=c0, [1]=scal1
#define OFF_CNT2 2319624u    // k4 done-counter (zeroed by K1)

__device__ __forceinline__ unsigned bump(float* ws, unsigned off) {
    return __hip_atomic_fetch_add((unsigned*)(ws + off), 1u,
                                  __ATOMIC_ACQ_REL, __HIP_MEMORY_SCOPE_AGENT);
}

// ===========================================================================
// K1: b<128: deg LDS-hist -> DEGP[b] | 128..255: u partials (64 rows each)
//     256..383: v = W@a2 (4 rows each) | b=384: c0 + zero CNT2
__global__ __launch_bounds__(1024) void k1(
        const float* __restrict__ lin_w, const float* __restrict__ att,
        const float* __restrict__ lin_b, const float* __restrict__ weight,
        const int* __restrict__ row, int E, float* __restrict__ ws) {
    __shared__ float smem[8192];
    const int b = blockIdx.x, tid = threadIdx.x;

    if (b < NDEG) {                              // ---- deg histogram ----
        #pragma unroll
        for (int m = 0; m < 8; ++m) smem[tid + m * 1024] = 0.f;
        __syncthreads();
        const int per4 = (E >> 2) / NDEG;        // 512 int4 chunks per block
        const int4* r4 = (const int4*)row;
        for (int q = tid; q < per4; q += 1024) {
            int4 r = r4[b * per4 + q];
            atomicAdd(&smem[r.x], 1.f); atomicAdd(&smem[r.y], 1.f);
            atomicAdd(&smem[r.z], 1.f); atomicAdd(&smem[r.w], 1.f);
        }
        if (b == NDEG - 1)                       // generic tail (empty here)
            for (int e = per4 * 4 * NDEG + tid; e < E; e += 1024)
                atomicAdd(&smem[row[e]], 1.f);
        __syncthreads();
        float4* dst = (float4*)(ws + OFF_DEGP) + b * 2048;
        dst[tid]        = ((float4*)smem)[tid];
        dst[tid + 1024] = ((float4*)smem)[tid + 1024];
    } else if (b < NDEG + NU) {                  // ---- u partials ----
        float4* lds4 = (float4*)smem;
        const int r0 = (b - NDEG) * 64;
        const int c4 = tid & 127, rg = tid >> 7;
        float4 acc = {0.f, 0.f, 0.f, 0.f};
        #pragma unroll
        for (int it = 0; it < 8; ++it) {
            int r = r0 + rg * 8 + it;
            float w = att[r];
            float4 v = ((const float4*)(lin_w + (size_t)r * INC))[c4];
            acc.x += w * v.x; acc.y += w * v.y; acc.z += w * v.z; acc.w += w * v.w;
        }
        lds4[tid] = acc;
        __syncthreads();
        #pragma unroll
        for (int off = 4; off > 0; off >>= 1) {
            if (rg < off) {
                float4 o = lds4[(rg + off) * 128 + c4];
                float4 m = lds4[tid];
                m.x += o.x; m.y += o.y; m.z += o.z; m.w += o.w;
                lds4[tid] = m;
            }
            __syncthreads();
        }
        if (rg == 0) ((float4*)(ws + OFF_UP))[(b - NDEG) * 128 + c4] = lds4[c4];
    } else if (b < NDEG + NU + NV) {             // ---- v[c] = W[c,:].a2 ----
        const int r0 = (b - NDEG - NU) * 4;
        const int rg = tid >> 8, kl = tid & 255;
        const int c = r0 + rg;
        const float4* wrow = (const float4*)(weight + (size_t)c * NN);
        const float4* a2   = (const float4*)(att + NN);
        float acc = 0.f;
        #pragma unroll
        for (int q = 0; q < 8; ++q) {
            float4 wv = wrow[kl + q * 256];
            float4 av = a2[kl + q * 256];
            acc += wv.x * av.x + wv.y * av.y + wv.z * av.z + wv.w * av.w;
        }
        smem[rg * 256 + kl] = acc;
        __syncthreads();
        for (int off = 128; off > 0; off >>= 1) {
            if (kl < off) smem[rg * 256 + kl] += smem[rg * 256 + kl + off];
            __syncthreads();
        }
        if (kl == 0) ws[OFF_V + c] = smem[rg * 256];
    } else {                                     // ---- c0 + zero CNT2 ----
        float v = 0.f;
        for (int i = tid; i < NN; i += 1024) v += lin_b[i] * att[i];
        smem[tid] = v;
        __syncthreads();
        for (int off = 512; off > 0; off >>= 1) {
            if (tid < off) smem[tid] += smem[tid + off];
            __syncthreads();
        }
        if (tid == 0) {
            ws[OFF_SC] = smem[0];
            *(unsigned*)(ws + OFF_CNT2) = 0u;    // kernel boundary orders this
        }
    }
}

// ===========================================================================
// K2 (256 blocks, 32 rows each): rebuild u from 128 UP partials (L2-hot);
// dinv for own 32 rows from DEGP (also exact-stored to OFF_DINV for K3);
// t partial (exact -> TP[b]) + xu. No done-counter, no tail.
__global__ __launch_bounds__(1024) void k2(
        const float* __restrict__ x, float* __restrict__ ws) {
    __shared__ float smem[8800];
    float4* lds4  = (float4*)smem;           // floats    0..4095 (t tree)
    float4* ured  = (float4*)(smem + 4096);  // floats 4096..8191
    float4* u4    = (float4*)(smem + 8192);  // floats 8192..8703
    float*  dinvl = smem + 8704;             // [32]
    float*  xured = smem + 8736;             // [64]
    const int b = blockIdx.x, tid = threadIdx.x;
    const int r0 = b * 32;
    const int c4 = tid & 127, rg = tid >> 7, lane = tid & 63;

    {                                        // u = sum of 128 partials
        const float4* up = (const float4*)(ws + OFF_UP);
        float4 a = {0.f, 0.f, 0.f, 0.f};
        #pragma unroll
        for (int q = 0; q < 16; ++q) {
            float4 v = up[(rg * 16 + q) * 128 + c4];
            a.x += v.x; a.y += v.y; a.z += v.z; a.w += v.w;
        }
        ured[rg * 128 + c4] = a;
    }
    if (tid >= 128 && tid < 160) {           // dinv for this block's 32 rows
        int rl = tid - 128;
        const float* degp = ws + OFF_DEGP;
        float d = 0.f;
        #pragma unroll 8
        for (int cp = 0; cp < NDEG; ++cp) d += degp[cp * NN + r0 + rl];
        float dvv = 1.f / sqrtf(d);
        dinvl[rl] = dvv;
        ws[OFF_DINV + r0 + rl] = dvv;        // exact-write slice for K3
    }
    __syncthreads();
    if (tid < 128) {
        float4 a = {0.f, 0.f, 0.f, 0.f};
        #pragma unroll
        for (int g = 0; g < 8; ++g) {
            float4 v = ured[g * 128 + tid];
            a.x += v.x; a.y += v.y; a.z += v.z; a.w += v.w;
        }
        u4[tid] = a;
    }
    __syncthreads();

    float4 accT = {0.f, 0.f, 0.f, 0.f};
    float xup[4];
    #pragma unroll
    for (int it = 0; it < 4; ++it) {
        int rl = rg + it * 8;
        float4 v = ((const float4*)(x + (size_t)(r0 + rl) * INC))[c4];
        float w = dinvl[rl];
        accT.x += w * v.x; accT.y += w * v.y; accT.z += w * v.z; accT.w += w * v.w;
        float4 uu = u4[c4];
        xup[it] = v.x * uu.x + v.y * uu.y + v.z * uu.z + v.w * uu.w;
    }
    #pragma unroll
    for (int it = 0; it < 4; ++it) {
        float a = xup[it];
        #pragma unroll
        for (int off = 32; off > 0; off >>= 1) a += __shfl_down(a, off);
        if (lane == 0) xured[rg * 8 + it * 2 + ((tid >> 6) & 1)] = a;
    }
    lds4[tid] = accT;
    __syncthreads();
    if (tid < 32) {                          // rl = rg + it*8
        int rl = tid, rg2 = rl & 7, it2 = rl >> 3;
        ws[OFF_XU + r0 + rl] =
            xured[rg2 * 8 + it2 * 2] + xured[rg2 * 8 + it2 * 2 + 1];
    }
    #pragma unroll
    for (int off = 4; off > 0; off >>= 1) {
        if (rg < off) {
            float4 o = lds4[(rg + off) * 128 + c4];
            float4 m = lds4[tid];
            m.x += o.x; m.y += o.y; m.z += o.z; m.w += o.w;
            lds4[tid] = m;
        }
        __syncthreads();
    }
    if (rg == 0) ((float4*)(ws + OFF_TP))[b * 128 + c4] = lds4[c4];
}

// ===========================================================================
// K3 (129 blocks): b<128: adv LDS-hist (dinv 32KB hot) -> exact ADVP[b].
//                  b==128: t finalize (sum 256 TP partials) + scal1 = t.v.
__global__ __launch_bounds__(1024) void k3(
        const int* __restrict__ row, const int* __restrict__ col, int E,
        float* __restrict__ ws) {
    __shared__ float smem[16384];
    const int b = blockIdx.x, tid = threadIdx.x;

    if (b < NADV) {                          // ---- adv histogram ----
        float* dl = smem;                    // dinv [8192]
        float* al = smem + 8192;             // adv  [8192]
        const float4* dv = (const float4*)(ws + OFF_DINV);
        ((float4*)dl)[tid]        = dv[tid];
        ((float4*)dl)[tid + 1024] = dv[tid + 1024];
        #pragma unroll
        for (int m = 0; m < 8; ++m) al[tid + m * 1024] = 0.f;
        __syncthreads();
        const int per4 = (E >> 2) / NADV;    // 512
        const int4* r4  = (const int4*)row;
        const int4* c4p = (const int4*)col;
        for (int q = tid; q < per4; q += 1024) {
            int4 r = r4[b * per4 + q];
            int4 c = c4p[b * per4 + q];
            atomicAdd(&al[r.x], dl[c.x]); atomicAdd(&al[r.y], dl[c.y]);
            atomicAdd(&al[r.z], dl[c.z]); atomicAdd(&al[r.w], dl[c.w]);
        }
        if (b == NADV - 1)
            for (int e = per4 * 4 * NADV + tid; e < E; e += 1024)
                atomicAdd(&al[row[e]], dl[col[e]]);
        __syncthreads();
        float4* dst = (float4*)(ws + OFF_ADVP) + b * 2048;
        dst[tid]        = ((float4*)al)[tid];
        dst[tid + 1024] = ((float4*)al)[tid + 1024];
    } else {                                 // ---- t + scal1 finalize ----
        const int colx = tid & 511, half = tid >> 9;
        const float* tp = ws + OFF_TP;
        float pv = 0.f;
        #pragma unroll 8
        for (int p = half * 128; p < half * 128 + 128; ++p)
            pv += tp[p * INC + colx];
        smem[tid] = pv;
        __syncthreads();
        if (tid < 512) {
            float tv = smem[tid] + smem[tid + 512];
            ws[OFF_T + tid] = tv;
            smem[tid] = tv * ws[OFF_V + tid];
        }
        __syncthreads();
        for (int off = 256; off > 0; off >>= 1) {
            if (tid < off) smem[tid] += smem[tid + off];
            __syncthreads();
        }
        if (tid == 0) ws[OFF_SC + 1] = smem[0];
    }
}

// ===========================================================================
// K4 (256 blocks, 32-wide k/i windows): s[k] full-c dot over W; adv = sum of
// 128 ADVP copies; alpha + s2 partial; last-done block: scal2 + out.
__global__ __launch_bounds__(1024) void k4(
        const float* __restrict__ weight, const float* __restrict__ bias,
        float* __restrict__ ws, float* __restrict__ out) {
    __shared__ float smem[4096];
    __shared__ int isLast;
    float* t_lds = smem;            // [512]
    float* gmat  = smem + 512;      // [32*33]
    float* amat  = smem + 1568;     // [32*33]
    const int b = blockIdx.x, tid = threadIdx.x;

    if (tid < 512) t_lds[tid] = ws[OFF_T + tid];
    __syncthreads();

    const int g = tid >> 5, kl = tid & 31;
    const int k = b * 32 + kl;
    float acc = 0.f;
    #pragma unroll
    for (int q = 0; q < 16; ++q) {
        int c = g + (q << 5);
        acc += t_lds[c] * weight[(size_t)c * NN + k];
    }
    gmat[g * 33 + kl] = acc;
    {   // adv copies: group g sums copies 4g..4g+3 for node kl
        const float* ap = ws + OFF_ADVP;
        int i = b * 32 + kl;
        float a = 0.f;
        #pragma unroll
        for (int j = 0; j < 4; ++j) a += ap[(size_t)(4 * g + j) * NN + i];
        amat[g * 33 + kl] = a;
    }
    __syncthreads();
    if (tid < 32) {
        float sv = 0.f, av = 0.f;
        #pragma unroll
        for (int j = 0; j < 32; ++j) {
            sv += gmat[j * 33 + tid];
            av += amat[j * 33 + tid];
        }
        int i = b * 32 + tid;
        float a  = ws[OFF_XU + i] + ws[OFF_SC] + av * ws[OFF_SC + 1];
        float lr = a > 0.f ? a : 0.2f * a;
        float part = sv * lr;
        ws[OFF_ADVF + i] = av;
        #pragma unroll
        for (int off = 16; off > 0; off >>= 1) part += __shfl_down(part, off);
        if (tid == 0) ws[OFF_S2P + b] = part;
    }
    __syncthreads();
    if (tid == 0) {
        unsigned old = bump(ws, OFF_CNT2);   // CNT2 zeroed by K1 this launch
        isLast = (old == NK4 - 1);
    }
    __syncthreads();
    if (!isLast) return;

    // ---- last block: scal2 (fixed-order tree, deterministic) + out ----
    smem[tid] = (tid < 256) ? ws[OFF_S2P + tid] : 0.f;
    __syncthreads();
    for (int off = 512; off > 0; off >>= 1) {
        if (tid < off) smem[tid] += smem[tid + off];
        __syncthreads();
    }
    const float s2 = smem[0];
    #pragma unroll
    for (int m = 0; m < 8; ++m) {
        int i = tid + m * 1024;
        float v = ws[OFF_ADVF + i] * s2 + bias[i];
        out[i] = v > 0.f ? v : 0.f;
    }
}

// ===========================================================================
extern "C" void kernel_launch(void* const* d_in, const int* in_sizes, int n_in,
                              void* d_out, int out_size, void* d_ws, size_t ws_size,
                              hipStream_t stream) {
    const float* x      = (const float*)d_in[0];   // [8192, 512]
    const int*   eidx   = (const int*)d_in[1];     // [2, E]
    const float* weight = (const float*)d_in[2];   // [512, 8192]
    const float* bias   = (const float*)d_in[3];   // [8192]
    const float* att    = (const float*)d_in[4];   // [16384]
    const float* lin_w  = (const float*)d_in[5];   // [8192, 512]
    const float* lin_b  = (const float*)d_in[6];   // [8192]

    const int E = in_sizes[1] / 2;
    const int* row = eidx;
    const int* col = eidx + E;
    float* ws  = (float*)d_ws;
    float* out = (float*)d_out;

    k1<<<NDEG + NU + NV + 1, 1024, 0, stream>>>(lin_w, att, lin_b, weight, row, E, ws);
    k2<<<NXB,      1024, 0, stream>>>(x, ws);
    k3<<<NADV + 1, 1024, 0, stream>>>(row, col, E, ws);
    k4<<<NK4,      1024, 0, stream>>>(weight, bias, ws, out);
}